// Round 17
// baseline (858.199 us; speedup 1.0000x reference)
//
#include <hip/hip_runtime.h>
#include <hip/hip_fp16.h>

#define TT 1024
#define BB 256
#define II 128
#define HH 256

typedef _Float16 f16x8 __attribute__((ext_vector_type(8)));
typedef _Float16 h2    __attribute__((ext_vector_type(2)));
typedef float    f32x4 __attribute__((ext_vector_type(4)));

union HU { h2 h; unsigned u; };
static __device__ __forceinline__ h2 as_h2(unsigned v) { HU t; t.u = v; return t.h; }
static __device__ __forceinline__ unsigned pack2f(float a, float b)
{
    HU t; t.h = h2{(_Float16)a, (_Float16)b}; return t.u;
}

// LDS-only barrier (global loads/stores stay in flight across steps).
#define LDS_BARRIER()                                            \
    do {                                                         \
        asm volatile("s_waitcnt lgkmcnt(0)" ::: "memory");       \
        __builtin_amdgcn_s_barrier();                            \
        __builtin_amdgcn_sched_barrier(0);                       \
    } while (0)

__device__ __forceinline__ float fast_tanh(float a)
{
    float e = __builtin_amdgcn_exp2f(a * 2.8853900817779268f);
    return 1.0f - 2.0f * __builtin_amdgcn_rcpf(e + 1.0f);
}

static __device__ __forceinline__ f16x8 cvt8(const float* p)
{
    float4 a = *(const float4*)p;
    float4 b = *(const float4*)(p + 4);
    f16x8 r;
    r[0]=(_Float16)a.x; r[1]=(_Float16)a.y; r[2]=(_Float16)a.z; r[3]=(_Float16)a.w;
    r[4]=(_Float16)b.x; r[5]=(_Float16)b.y; r[6]=(_Float16)b.z; r[7]=(_Float16)b.w;
    return r;
}

// ---------- Pre-GEMM: xw = x @ W^T + (bW + bV), fp32 into seq region ----------
// Verified passing since R13 (~87 us, HBM-bound).
__global__ __launch_bounds__(256, 1)
void xw_gemm(const float* __restrict__ x, const float* __restrict__ W,
             const float* __restrict__ bW, const float* __restrict__ bV,
             float* __restrict__ xw)
{
    __shared__ _Float16 Wl[HH * II];
    const int tid  = threadIdx.x;
    const int l    = tid & 63;
    const int wv   = (__builtin_amdgcn_readfirstlane(tid) >> 6) & 3;
    const int lr   = l & 15;
    const int kgrp = l >> 4;

    {
        const int row = tid;
        const float4* src = (const float4*)(W + (size_t)row * II);
        unsigned* dst = (unsigned*)Wl;
        const int sw = (row & 7) << 4;
#pragma unroll
        for (int q = 0; q < II / 4; ++q) {
            float4 v = src[q];
            dst[(row * 256 + ((q * 8) ^ sw)) >> 2]     = pack2f(v.x, v.y);
            dst[(row * 256 + ((q * 8 + 4) ^ sw)) >> 2] = pack2f(v.z, v.w);
        }
    }
    __syncthreads();

    const size_t Mbase = (size_t)blockIdx.x * 64;
    const size_t arow  = Mbase + 16 * wv + lr;

    f16x8 afr[4];
#pragma unroll
    for (int kc = 0; kc < 4; ++kc)
        afr[kc] = cvt8(x + arow * II + kc * 32 + kgrp * 8);

    f32x4 acc[16];
#pragma unroll
    for (int nt = 0; nt < 16; ++nt) acc[nt] = f32x4{0.f, 0.f, 0.f, 0.f};

#pragma unroll
    for (int nt = 0; nt < 16; ++nt) {
        const int col = nt * 16 + lr;
        const int sw  = (col & 7) << 4;
#pragma unroll
        for (int kc = 0; kc < 4; ++kc) {
            f16x8 bfr = *(const f16x8*)((const char*)Wl + col * 256 +
                                        ((kc * 64 + kgrp * 16) ^ sw));
            acc[nt] = __builtin_amdgcn_mfma_f32_16x16x32_f16(afr[kc], bfr, acc[nt], 0, 0, 0);
        }
    }
#pragma unroll
    for (int nt = 0; nt < 16; ++nt) {
        const float bias = bW[nt * 16 + lr] + bV[nt * 16 + lr];
#pragma unroll
        for (int r = 0; r < 4; ++r) {
            size_t row = Mbase + 16 * wv + kgrp * 4 + r;
            xw[row * HH + nt * 16 + lr] = acc[nt][r] + bias;
        }
    }
}

// ---------- Recurrence: pk_fma_f16 engine + finalize spread across all waves ----------
// 256 WGs (one per CU/batch row) x 512 thr (8 waves, 2/SIMD).
// V-phase: wave w owns K-slice [32w,32w+32); thread owns outputs 4l..4l+3
// (Vh[4][16] f16x2 = 64 VGPRs). v_pk_fma_f16 (full-rate, 2 MACs/2cyc = 2x
// dot2's MAC issue rate) accumulating in f16x2 (8-add chains, err ~1e-4),
// halves combined in f32 before pbuf.
// Finalize: wave w finalizes outputs 32w..32w+31 on lanes 0-31 (pbuf reads
// hit all 32 banks; seq stores contiguous per wave) -- no idle-wave segment.
// Parity xw registers give 2-step prefetch distance. 2 LDS-only barriers/step.
__global__ __launch_bounds__(512, 2)
void rnn_v2(const float* __restrict__ V, float* __restrict__ out)
{
    const int b   = blockIdx.x;
    const int tid = threadIdx.x;
    const int l   = tid & 63;
    const int w   = (__builtin_amdgcn_readfirstlane(tid) >> 6) & 7;
    const int lb  = 8 * w;            // lanes holding this wave's h pairs
    const int fo  = 32 * w + (l & 31);  // finalize output (lanes 0-31)
    const bool fact = (l < 32);

    __shared__ __align__(16) _Float16 hbuf[2][HH];
    __shared__ __align__(16) float    pbuf[8][HH];

    h2 Vh[4][16];  // V[4l+c][32w + 2m, 2m+1] as f16 pairs
#pragma unroll
    for (int c = 0; c < 4; ++c) {
        const int j = 4 * l + c;
        const float* vr = V + (size_t)j * HH + 32 * w;
#pragma unroll
        for (int m = 0; m < 16; ++m)
            Vh[c][m] = h2{(_Float16)vr[2 * m], (_Float16)vr[2 * m + 1]};
    }

    if (tid < HH) { hbuf[0][tid] = (_Float16)0.f; hbuf[1][tid] = (_Float16)0.f; }
    __syncthreads();

    float* __restrict__ seq = out;                         // (T,B,H) fp32
    float* __restrict__ fin = out + (size_t)TT * BB * HH;  // (B,H) fp32

    // Parity xw prefetch (bias pre-folded by the GEMM).
    float XA = 0.f, XB = 0.f;
    if (fact) {
        XA = seq[((size_t)0 * BB + b) * HH + fo];
        XB = seq[((size_t)1 * BB + b) * HH + fo];
    }

#define RSTEP(P, X, T)                                                          \
    {                                                                           \
        uint2 hv = *(const uint2*)&hbuf[P][4 * l]; /* h[4l..4l+3] */            \
        h2 a0[4], a1[4];                                                        \
        _Pragma("unroll")                                                       \
        for (int c = 0; c < 4; ++c) { a0[c] = h2{0, 0}; a1[c] = h2{0, 0}; }     \
        _Pragma("unroll")                                                       \
        for (int i2 = 0; i2 < 8; ++i2) {                                        \
            unsigned s0 = (unsigned)__builtin_amdgcn_readlane((int)hv.x, lb + i2); \
            unsigned s1 = (unsigned)__builtin_amdgcn_readlane((int)hv.y, lb + i2); \
            h2 b0 = as_h2(s0), b1 = as_h2(s1);                                  \
            _Pragma("unroll")                                                   \
            for (int c = 0; c < 4; ++c) {                                       \
                a0[c] = __builtin_elementwise_fma(b0, Vh[c][2 * i2],     a0[c]); \
                a1[c] = __builtin_elementwise_fma(b1, Vh[c][2 * i2 + 1], a1[c]); \
            }                                                                   \
        }                                                                       \
        f32x4 tot;                                                              \
        _Pragma("unroll")                                                       \
        for (int c = 0; c < 4; ++c) {                                           \
            h2 s = a0[c] + a1[c];                                               \
            tot[c] = (float)s[0] + (float)s[1];                                 \
        }                                                                       \
        *(f32x4*)&pbuf[w][4 * l] = tot;                                         \
        LDS_BARRIER(); /* pbuf visible */                                       \
        if (fact) {                                                             \
            float p0 = pbuf[0][fo], p1 = pbuf[1][fo];                           \
            float p2 = pbuf[2][fo], p3 = pbuf[3][fo];                           \
            float p4 = pbuf[4][fo], p5 = pbuf[5][fo];                           \
            float p6 = pbuf[6][fo], p7 = pbuf[7][fo];                           \
            float r  = (((p0 + p1) + (p2 + p3)) + ((p4 + p5) + (p6 + p7))) + X; \
            float hf = fast_tanh(r);                                            \
            hbuf[(P) ^ 1][fo] = (_Float16)hf;                                   \
            seq[((size_t)(T) * BB + b) * HH + fo] = hf;                         \
            if ((T) == TT - 1) fin[(size_t)b * HH + fo] = hf;                   \
            const int tp = ((T) + 2 < TT) ? (T) + 2 : (TT - 1);                 \
            X = seq[((size_t)tp * BB + b) * HH + fo];                           \
        }                                                                       \
        LDS_BARRIER(); /* h(T) visible */                                       \
    }

#pragma unroll 1
    for (int t = 0; t < TT; t += 2) {
        RSTEP(0, XA, t);
        RSTEP(1, XB, t + 1);
    }
#undef RSTEP
}

extern "C" void kernel_launch(void* const* d_in, const int* in_sizes, int n_in,
                              void* d_out, int out_size, void* d_ws, size_t ws_size,
                              hipStream_t stream)
{
    const float* x  = (const float*)d_in[0];
    const float* W  = (const float*)d_in[1];
    const float* bW = (const float*)d_in[2];
    const float* V  = (const float*)d_in[3];
    const float* bV = (const float*)d_in[4];
    float* out = (float*)d_out;

    xw_gemm<<<dim3((TT * BB) / 64), dim3(256), 0, stream>>>(x, W, bW, bV, out);
    rnn_v2<<<dim3(BB), dim3(512), 0, stream>>>(V, out);
}

// Round 18
// 731.194 us; speedup vs baseline: 1.1737x; 1.1737x over previous
//
#include <hip/hip_runtime.h>
#include <hip/hip_fp16.h>

#define TT 1024
#define BB 256
#define II 128
#define HH 256

typedef _Float16 f16x8 __attribute__((ext_vector_type(8)));
typedef _Float16 h2    __attribute__((ext_vector_type(2)));
typedef __fp16   fp16x2 __attribute__((ext_vector_type(2)));
typedef float    f32x4 __attribute__((ext_vector_type(4)));

union HU { h2 h; unsigned u; };
static __device__ __forceinline__ h2 as_h2(unsigned v) { HU t; t.u = v; return t.h; }
static __device__ __forceinline__ unsigned pack2f(float a, float b)
{
    HU t; t.h = h2{(_Float16)a, (_Float16)b}; return t.u;
}
union PK { fp16x2 h; unsigned u; };
static __device__ __forceinline__ unsigned pkrtz(float a, float b)
{
    PK t; t.h = __builtin_amdgcn_cvt_pkrtz(a, b); return t.u;
}
static __device__ __forceinline__ float fdot2u(unsigned a, unsigned b, float c)
{
    return __builtin_amdgcn_fdot2(as_h2(a), as_h2(b), c, false);
}

// LDS-only barrier (global loads/stores stay in flight across steps).
#define LDS_BARRIER()                                            \
    do {                                                         \
        asm volatile("s_waitcnt lgkmcnt(0)" ::: "memory");       \
        __builtin_amdgcn_s_barrier();                            \
        __builtin_amdgcn_sched_barrier(0);                       \
    } while (0)

__device__ __forceinline__ float fast_tanh(float a)
{
    float e = __builtin_amdgcn_exp2f(a * 2.8853900817779268f);
    return 1.0f - 2.0f * __builtin_amdgcn_rcpf(e + 1.0f);
}

static __device__ __forceinline__ f16x8 cvt8(const float* p)
{
    float4 a = *(const float4*)p;
    float4 b = *(const float4*)(p + 4);
    f16x8 r;
    r[0]=(_Float16)a.x; r[1]=(_Float16)a.y; r[2]=(_Float16)a.z; r[3]=(_Float16)a.w;
    r[4]=(_Float16)b.x; r[5]=(_Float16)b.y; r[6]=(_Float16)b.z; r[7]=(_Float16)b.w;
    return r;
}

// ---------- Pre-GEMM: xw = x @ W^T + (bW + bV), fp32 into seq region ----------
// Verified passing since R13 (~87 us, HBM-bound).
__global__ __launch_bounds__(256, 1)
void xw_gemm(const float* __restrict__ x, const float* __restrict__ W,
             const float* __restrict__ bW, const float* __restrict__ bV,
             float* __restrict__ xw)
{
    __shared__ _Float16 Wl[HH * II];
    const int tid  = threadIdx.x;
    const int l    = tid & 63;
    const int wv   = (__builtin_amdgcn_readfirstlane(tid) >> 6) & 3;
    const int lr   = l & 15;
    const int kgrp = l >> 4;

    {
        const int row = tid;
        const float4* src = (const float4*)(W + (size_t)row * II);
        unsigned* dst = (unsigned*)Wl;
        const int sw = (row & 7) << 4;
#pragma unroll
        for (int q = 0; q < II / 4; ++q) {
            float4 v = src[q];
            dst[(row * 256 + ((q * 8) ^ sw)) >> 2]     = pack2f(v.x, v.y);
            dst[(row * 256 + ((q * 8 + 4) ^ sw)) >> 2] = pack2f(v.z, v.w);
        }
    }
    __syncthreads();

    const size_t Mbase = (size_t)blockIdx.x * 64;
    const size_t arow  = Mbase + 16 * wv + lr;

    f16x8 afr[4];
#pragma unroll
    for (int kc = 0; kc < 4; ++kc)
        afr[kc] = cvt8(x + arow * II + kc * 32 + kgrp * 8);

    f32x4 acc[16];
#pragma unroll
    for (int nt = 0; nt < 16; ++nt) acc[nt] = f32x4{0.f, 0.f, 0.f, 0.f};

#pragma unroll
    for (int nt = 0; nt < 16; ++nt) {
        const int col = nt * 16 + lr;
        const int sw  = (col & 7) << 4;
#pragma unroll
        for (int kc = 0; kc < 4; ++kc) {
            f16x8 bfr = *(const f16x8*)((const char*)Wl + col * 256 +
                                        ((kc * 64 + kgrp * 16) ^ sw));
            acc[nt] = __builtin_amdgcn_mfma_f32_16x16x32_f16(afr[kc], bfr, acc[nt], 0, 0, 0);
        }
    }
#pragma unroll
    for (int nt = 0; nt < 16; ++nt) {
        const float bias = bW[nt * 16 + lr] + bV[nt * 16 + lr];
#pragma unroll
        for (int r = 0; r < 4; ++r) {
            size_t row = Mbase + 16 * wv + kgrp * 4 + r;
            xw[row * HH + nt * 16 + lr] = acc[nt][r] + bias;
        }
    }
}

// ---------- Recurrence: dot2 engine, ONE barrier/step, feeds from own regs ----------
// 256 WGs (one per CU/batch row) x 512 thr (8 waves, 2/SIMD).
// V-phase: wave w owns K-slice [32w,32w+32); thread owns outputs 4l..4l+3
// (16 readlane + 64 dot2). Partials -> pbuf[parity][w][..] (double-buffered:
// one barrier/step is race-free; lgkmcnt(0) drains reads before the barrier).
// Finalize: wave w finalizes ITS OWN broadcast set h[32w..32w+31] on lanes
// 0-31 (pbuf reads lane j -> bank j, conflict-free), then packs f16 pairs
// in-register (shfl_xor + cvt_pkrtz) -- next step's readlane feeds come from
// the wave's own pk register. hbuf and the second barrier are GONE.
__global__ __launch_bounds__(512, 2)
void rnn_v3(const float* __restrict__ V, float* __restrict__ out)
{
    const int b   = blockIdx.x;
    const int tid = threadIdx.x;
    const int l   = tid & 63;
    const int w   = (__builtin_amdgcn_readfirstlane(tid) >> 6) & 7;
    const int j   = l & 31;         // finalize sub-lane
    const int fo  = 32 * w + j;     // this wave's finalize output
    const bool fact = (l < 32);

    __shared__ __align__(16) float pbuf[2][8][HH];  // 16 KB, parity-buffered

    unsigned Vh[4][16];  // V[4l+c][32w + 2m, 2m+1] packed f16
#pragma unroll
    for (int c = 0; c < 4; ++c) {
        const int jo = 4 * l + c;
        const float* vr = V + (size_t)jo * HH + 32 * w;
#pragma unroll
        for (int m = 0; m < 16; ++m) Vh[c][m] = pack2f(vr[2 * m], vr[2 * m + 1]);
    }

    float* __restrict__ seq = out;                         // (T,B,H) fp32
    float* __restrict__ fin = out + (size_t)TT * BB * HH;  // (B,H) fp32

    // Broadcast register: lane 2i holds packed (h[32w+2i], h[32w+2i+1]).
    unsigned pk = 0u;  // h(-1) = 0

    // Parity xw prefetch (bias pre-folded by the GEMM).
    float XA = 0.f, XB = 0.f;
    if (fact) {
        XA = seq[((size_t)0 * BB + b) * HH + fo];
        XB = seq[((size_t)1 * BB + b) * HH + fo];
    }

#define RSTEP(P, X, T)                                                          \
    {                                                                           \
        float va[4][2] = {{0.f,0.f},{0.f,0.f},{0.f,0.f},{0.f,0.f}};             \
        _Pragma("unroll")                                                       \
        for (int i = 0; i < 16; ++i) {                                          \
            unsigned s = (unsigned)__builtin_amdgcn_readlane((int)pk, 2 * i);   \
            _Pragma("unroll")                                                   \
            for (int c = 0; c < 4; ++c)                                         \
                va[c][i & 1] = fdot2u(s, Vh[c][i], va[c][i & 1]);               \
        }                                                                       \
        f32x4 tot;                                                              \
        _Pragma("unroll")                                                       \
        for (int c = 0; c < 4; ++c) tot[c] = va[c][0] + va[c][1];               \
        *(f32x4*)&pbuf[P][w][4 * l] = tot;                                      \
        LDS_BARRIER(); /* pbuf[P] visible; prior reads drained */               \
        if (fact) {                                                             \
            float p0 = pbuf[P][0][fo], p1 = pbuf[P][1][fo];                     \
            float p2 = pbuf[P][2][fo], p3 = pbuf[P][3][fo];                     \
            float p4 = pbuf[P][4][fo], p5 = pbuf[P][5][fo];                     \
            float p6 = pbuf[P][6][fo], p7 = pbuf[P][7][fo];                     \
            float r  = (((p0 + p1) + (p2 + p3)) + ((p4 + p5) + (p6 + p7))) + X; \
            float hf = fast_tanh(r);                                            \
            seq[((size_t)(T) * BB + b) * HH + fo] = hf;                         \
            if ((T) == TT - 1) fin[(size_t)b * HH + fo] = hf;                   \
            const int tp = ((T) + 2 < TT) ? (T) + 2 : (TT - 1);                 \
            X = seq[((size_t)tp * BB + b) * HH + fo];                           \
            float nb = __shfl_xor(hf, 1, 64);                                   \
            float lo = (j & 1) ? nb : hf;                                       \
            float hi = (j & 1) ? hf : nb;                                       \
            pk = pkrtz(lo, hi);                                                 \
        }                                                                       \
    }

#pragma unroll 1
    for (int t = 0; t < TT; t += 2) {
        RSTEP(0, XA, t);
        RSTEP(1, XB, t + 1);
    }
#undef RSTEP
}

extern "C" void kernel_launch(void* const* d_in, const int* in_sizes, int n_in,
                              void* d_out, int out_size, void* d_ws, size_t ws_size,
                              hipStream_t stream)
{
    const float* x  = (const float*)d_in[0];
    const float* W  = (const float*)d_in[1];
    const float* bW = (const float*)d_in[2];
    const float* V  = (const float*)d_in[3];
    const float* bV = (const float*)d_in[4];
    float* out = (float*)d_out;

    xw_gemm<<<dim3((TT * BB) / 64), dim3(256), 0, stream>>>(x, W, bW, bV, out);
    rnn_v3<<<dim3(BB), dim3(512), 0, stream>>>(V, out);
}